// Round 6
// baseline (1322.242 us; speedup 1.0000x reference)
//
#include <hip/hip_runtime.h>
#include <hip/hip_bf16.h>
#include <hip/hip_fp16.h>

// Problem constants
#define B_    256
#define TR    512
#define P_    128
#define H_    128
#define NG    384      // 3*H
#define KI    256      // 2*P
#define TA    64
#define PSTD  32
#define PSTAT 16
#define HH    64       // HEAD_H
#define FDIM  176      // H + P_STD + P_STATIC

#define NB    8            // batches per scan block (MFMA N-cols used)
#define NSCAN (B_/NB)      // 32 scan blocks

// ---- scan LDS staging geometry (TB = 2 steps per tile) ----
#define TB       2
#define NTILE    (TR/TB)        // 256
#define GIHT_ROW 1056           // 768 gi + 256 ht + 32 pad   (bytes)
#define GIHT_SEQ (TB*GIHT_ROW + 32)   // 2144; %32dw=24 -> 2-way banks
#define GIHT_SZ  (8*GIHT_SEQ)   // 17152
#define DL_ROW   544            // 512 delta + 32 pad
#define DL_SEQ   (TB*DL_ROW + 32)     // 1120
#define DL_SZ    (8*DL_SEQ)     // 8960
#define SBUF     (GIHT_SZ + DL_SZ)    // 26112; x2 buffers = 52224 B

typedef __attribute__((ext_vector_type(8))) short short8;
typedef __attribute__((ext_vector_type(4))) float f32x4;
typedef _Float16 f16;
typedef __attribute__((ext_vector_type(8))) _Float16 f16x8;

// ---- helpers ----
__device__ __forceinline__ float bf2f(ushort u) {
    union { uint i; float f; } v; v.i = ((uint)u) << 16; return v.f;
}
__device__ __forceinline__ ushort f2bf(float f) {
    union { float f; uint u; } v; v.f = f;
    uint u = v.u;
    uint r = (u + 0x7fffu + ((u >> 16) & 1u)) >> 16;  // RTNE
    return (ushort)r;
}
__device__ __forceinline__ float bflo(uint u) {
    union { uint i; float f; } v; v.i = u << 16; return v.f;
}
__device__ __forceinline__ float bfhi(uint u) {
    union { uint i; float f; } v; v.i = u & 0xffff0000u; return v.f;
}
__device__ __forceinline__ float tanhf_fast(float x) {
    float ax = fabsf(x);
    float e = __expf(-2.f * ax);
    float r = (1.f - e) / (1.f + e);
    return copysignf(r, x);
}
// branch-free scan transcendentals (v_exp + v_rcp)
__device__ __forceinline__ float sigf2(float x) {
    return __builtin_amdgcn_rcpf(1.f + __expf(-x));
}
__device__ __forceinline__ float tanh2(float x) {
    // tanh(x) = 1 - 2/(exp(2x)+1); saturates correctly at +/-inf, no NaN
    return 1.f - 2.f * __builtin_amdgcn_rcpf(1.f + __expf(2.f * x));
}
// LDS-only barrier that does NOT drain vmcnt (raw s_barrier; lgkm wait only).
__device__ __forceinline__ void bar_lds() {
    __builtin_amdgcn_sched_barrier(0);
    __asm__ volatile("s_waitcnt lgkmcnt(0)");
    __builtin_amdgcn_s_barrier();
    __builtin_amdgcn_sched_barrier(0);
}

// ---------------------------------------------------------------------------
// Kernel 0: convert Wih, Wd to bf16; fold bhh_{r,z} into bih -> bihc.
// ---------------------------------------------------------------------------
__global__ __launch_bounds__(256) void k_convert(
    const float* __restrict__ Wih, const float* __restrict__ Wd,
    const float* __restrict__ bih, const float* __restrict__ bhh,
    ushort* __restrict__ wih_b, ushort* __restrict__ wd_b,
    float* __restrict__ bihc)
{
    int i = blockIdx.x * 256 + threadIdx.x;
    if (i < NG * KI) wih_b[i] = f2bf(Wih[i]);
    if (i < H_ * P_) wd_b[i]  = f2bf(Wd[i]);
    if (i < NG) bihc[i] = bih[i] + (i < 2 * H_ ? bhh[i] : 0.f);
}

// ---------------------------------------------------------------------------
// Kernel 1: fused elementwise + GEMM (MFMA bf16 16x16x32). [unchanged]
// ---------------------------------------------------------------------------
#define SA 392   // padded LDS row stride in bf16 elems (also >= 384 for staging)

__global__ __launch_bounds__(256, 2) void k_gemm(
    const float* __restrict__ X, const float* __restrict__ M,
    const float* __restrict__ DT, const float* __restrict__ xmean,
    const ushort* __restrict__ wih_b, const ushort* __restrict__ wd_b,
    const float* __restrict__ bih, const float* __restrict__ bd,
    ushort* __restrict__ gi_ws, ushort* __restrict__ htil_ws,
    float* __restrict__ delta_ws)
{
    __shared__ __align__(16) ushort sA[64 * SA];   // 50176 B; reused for staging
    const int tid = threadIdx.x;
    const long r0 = (long)blockIdx.x * 64;

    // ---- build A tile (64 rows x [x_dec|m|x_hat]) + delta (coalesced f32) ----
    #pragma unroll 4
    for (int i = 0; i < 32; ++i) {
        int idx = i * 256 + tid;
        int rl = idx >> 7, k = idx & 127;
        long g = (r0 + rl) * 128 + k;
        float x = X[g], m = M[g], dt = DT[g], xm = xmean[k];
        float delta = 1.f / (1.f + __expf(dt));   // sigmoid(-dt)
        float xh = m * x + (1.f - m) * xm;
        float xd = m * x + (1.f - m) * (delta * xh + (1.f - delta) * xm);
        sA[rl * SA + k]       = f2bf(xd);
        sA[rl * SA + 128 + k] = f2bf(m);
        sA[rl * SA + 256 + k] = f2bf(xh);
        delta_ws[g] = delta;
    }
    __syncthreads();

    const int wv   = tid >> 6;        // wave 0..3 -> gi col slice [96w,96w+96)
    const int lane = tid & 63;
    const int l16  = lane & 15;       // A row idx / B col idx / C col idx
    const int q    = lane >> 4;       // quad: A k-offset q*8 / C rows q*4+reg

    // ---- gi: acc[rt][nt], rt = row-tile (16 rows), nt = col-tile in slice ----
    f32x4 acc[4][6];
    #pragma unroll
    for (int rt = 0; rt < 4; ++rt)
        #pragma unroll
        for (int nt = 0; nt < 6; ++nt) acc[rt][nt] = (f32x4){0.f, 0.f, 0.f, 0.f};

    const int nb = 96 * wv;
    #pragma unroll
    for (int ks = 0; ks < 8; ++ks) {
        short8 a[4];
        #pragma unroll
        for (int rt = 0; rt < 4; ++rt)
            a[rt] = *(const short8*)&sA[(rt * 16 + l16) * SA + ks * 32 + q * 8];
        #pragma unroll
        for (int nt = 0; nt < 6; ++nt) {
            const short8 b = *(const short8*)&wih_b[(size_t)(nb + nt * 16 + l16) * KI + ks * 32 + q * 8];
            #pragma unroll
            for (int rt = 0; rt < 4; ++rt)
                acc[rt][nt] = __builtin_amdgcn_mfma_f32_16x16x32_bf16(a[rt], b, acc[rt][nt], 0, 0, 0);
        }
    }

    // ---- htil: acc2[rt][nt2], col slice [32w,32w+32), K=128 (A cols 256+) ----
    f32x4 acc2[4][2];
    #pragma unroll
    for (int rt = 0; rt < 4; ++rt)
        #pragma unroll
        for (int nt = 0; nt < 2; ++nt) acc2[rt][nt] = (f32x4){0.f, 0.f, 0.f, 0.f};

    const int nb2 = 32 * wv;
    #pragma unroll
    for (int ks = 0; ks < 4; ++ks) {
        short8 a[4];
        #pragma unroll
        for (int rt = 0; rt < 4; ++rt)
            a[rt] = *(const short8*)&sA[(rt * 16 + l16) * SA + 256 + ks * 32 + q * 8];
        #pragma unroll
        for (int nt = 0; nt < 2; ++nt) {
            const short8 b = *(const short8*)&wd_b[(size_t)(nb2 + nt * 16 + l16) * P_ + ks * 32 + q * 8];
            #pragma unroll
            for (int rt = 0; rt < 4; ++rt)
                acc2[rt][nt] = __builtin_amdgcn_mfma_f32_16x16x32_bf16(a[rt], b, acc2[rt][nt], 0, 0, 0);
        }
    }

    __syncthreads();   // all sA reads done; safe to overwrite with staging

    // ---- stage gi (bf16, [row][n] unpadded 64x384) into sA region ----
    ushort* sOut = sA;
    #pragma unroll
    for (int nt = 0; nt < 6; ++nt) {
        const int n = nb + nt * 16 + l16;
        const float bi = bih[n];
        #pragma unroll
        for (int rt = 0; rt < 4; ++rt) {
            #pragma unroll
            for (int reg = 0; reg < 4; ++reg) {
                int row = rt * 16 + q * 4 + reg;
                sOut[row * NG + n] = f2bf(acc[rt][nt][reg] + bi);
            }
        }
    }
    __syncthreads();

    // ---- coalesced contiguous store: 64*384 bf16 = 3072 uint4 ----
    {
        uint4* dst = (uint4*)(gi_ws + (size_t)r0 * NG);
        const uint4* src = (const uint4*)sOut;
        #pragma unroll
        for (int i = 0; i < 12; ++i) dst[tid + 256 * i] = src[tid + 256 * i];
    }
    __syncthreads();   // uint4 LDS reads retired; safe to restage

    // ---- stage htil (bf16, [row][n] 64x128) ----
    #pragma unroll
    for (int nt = 0; nt < 2; ++nt) {
        const int n = nb2 + nt * 16 + l16;
        const float bi = bd[n];
        #pragma unroll
        for (int rt = 0; rt < 4; ++rt) {
            #pragma unroll
            for (int reg = 0; reg < 4; ++reg) {
                int row = rt * 16 + q * 4 + reg;
                sOut[row * P_ + n] = f2bf(tanhf_fast(acc2[rt][nt][reg] + bi));
            }
        }
    }
    __syncthreads();

    // ---- coalesced store: 64*128 bf16 = 1024 uint4 ----
    {
        uint4* dst = (uint4*)(htil_ws + (size_t)r0 * P_);
        const uint4* src = (const uint4*)sOut;
        #pragma unroll
        for (int i = 0; i < 4; ++i) dst[tid + 256 * i] = src[tid + 256 * i];
    }
}

// ---------------------------------------------------------------------------
// Kernel 2: recurrent scan v8 — MFMA matvec + LDS tile staging (the proven
//   431us-baseline staging skeleton, MFMA replacing the VALU matvec).
//   v7 post-mortem: VGPR_Count=84 vs ~150+ demand -> allocator still
//   spilled/collapsed the register prefetch pipeline; per-step critical path
//   kept a full memory round trip (2283 cy/step, all pipes <6%).
//   v8: gates staged into LDS in coalesced wave-uniform tiles (wave w stages
//   seq w; lanes 0-47 gi row, 48-63 ht row, 0-31 dl row). Per-step gate
//   access is ds_read (~60cy). Global latency amortized once per TB=2 steps,
//   hidden behind ~2 steps of compute; implicit vmcnt before ds_write is
//   precise (only Hraw stores are newer). Register demand ~140 -> no spills.
//   All lanes compute with bbw duplication (no divergence; rows 8-15 of
//   h_lds carry valid duplicates); only Hraw store is act-guarded.
// ---------------------------------------------------------------------------

#define STAGE_LOAD(TT) {                                                     \
    const size_t t0_ = (size_t)(TT) * TB;                                    \
    _Pragma("unroll")                                                        \
    for (int t = 0; t < TB; ++t) {                                           \
        const ushort* grow_ = gseq + (t0_ + t) * NG;                         \
        const ushort* hrow_ = hseq + (t0_ + t) * P_;                         \
        const char* src_ = (lane < 48) ? (const char*)(grow_ + lane * 8)     \
                                       : (const char*)(hrow_ + (lane - 48) * 8); \
        sg[t] = *(const uint4*)src_;                                         \
        if (lane < 32)                                                       \
            sd[t] = *(const uint4*)(dseq + (t0_ + t) * P_ + lane * 4);       \
    }                                                                        \
}

#define STAGE_WRITE(BUFP) {                                                  \
    char* b_ = (char*)(BUFP);                                                \
    _Pragma("unroll")                                                        \
    for (int t = 0; t < TB; ++t) {                                           \
        *(uint4*)(b_ + w * GIHT_SEQ + t * GIHT_ROW + lane * 16) = sg[t];     \
        if (lane < 32)                                                       \
            *(uint4*)(b_ + GIHT_SZ + w * DL_SEQ + t * DL_ROW + lane * 16) = sd[t]; \
    }                                                                        \
}

// One recurrence step. Gates for step (tile,TS) from scur; htil/delta for
// the NEXT step from HDBASE row HDTS (scur ts+1, or snxt ts0 at tile end).
#define STEP(TGLOB, TS, HDBASE, HDTS, PC, PN) {                              \
    bar_lds();                                                               \
    f16x8 bf[4];                                                             \
    _Pragma("unroll")                                                        \
    for (int ks = 0; ks < 4; ++ks)                                           \
        bf[ks] = *(const f16x8*)&h_lds[PC][bb][ks * 32 + q * 8];             \
    const char* gb_ = scur + bbw * GIHT_SEQ + (TS) * GIHT_ROW + wq2;         \
    uint2 g_r = *(const uint2*)(gb_);                                        \
    uint2 g_z = *(const uint2*)(gb_ + 256);                                  \
    uint2 g_n = *(const uint2*)(gb_ + 512);                                  \
    const char* hb_ = (const char*)(HDBASE) + bbw * GIHT_SEQ + (HDTS) * GIHT_ROW + wq2; \
    uint2 g_h = *(const uint2*)(hb_ + 768);                                  \
    float4 g_d = *(const float4*)((const char*)(HDBASE) + GIHT_SZ + bbw * DL_SEQ + (HDTS) * DL_ROW + wq4); \
    f32x4 ac0 = (f32x4){bflo(g_r.x), bfhi(g_r.x), bflo(g_r.y), bfhi(g_r.y)}; \
    f32x4 ac1 = (f32x4){bflo(g_z.x), bfhi(g_z.x), bflo(g_z.y), bfhi(g_z.y)}; \
    f32x4 ac2 = (f32x4){bhn[0], bhn[1], bhn[2], bhn[3]};                     \
    _Pragma("unroll")                                                        \
    for (int ks = 0; ks < 4; ++ks) {                                         \
        ac0 = __builtin_amdgcn_mfma_f32_16x16x32_f16(aF[0][ks], bf[ks], ac0, 0, 0, 0); \
        ac1 = __builtin_amdgcn_mfma_f32_16x16x32_f16(aF[1][ks], bf[ks], ac1, 0, 0, 0); \
        ac2 = __builtin_amdgcn_mfma_f32_16x16x32_f16(aF[2][ks], bf[ks], ac2, 0, 0, 0); \
    }                                                                        \
    {                                                                        \
        float gn_[4] = {bflo(g_n.x), bfhi(g_n.x), bflo(g_n.y), bfhi(g_n.y)}; \
        float ht_[4] = {bflo(g_h.x), bfhi(g_h.x), bflo(g_h.y), bfhi(g_h.y)}; \
        float dl_[4] = {g_d.x, g_d.y, g_d.z, g_d.w};                         \
        float hnv[4];                                                        \
        _Pragma("unroll")                                                    \
        for (int r = 0; r < 4; ++r) {                                        \
            float rg = sigf2(ac0[r]);                                        \
            float zg = sigf2(ac1[r]);                                        \
            float np = gn_[r] + rg * ac2[r];                                 \
            float ng = tanh2(np);                                            \
            float hn = ng + zg * (hpre[r] - ng);                             \
            hnv[r] = hn;                                                     \
            hpre[r] = ht_[r] + dl_[r] * (hn - ht_[r]);                       \
        }                                                                    \
        if (act)                                                             \
            *(float4*)&Hraw[(rowb + (TGLOB)) * P_ + j0] =                    \
                make_float4(hnv[0], hnv[1], hnv[2], hnv[3]);                 \
        f16 p0 = (f16)hpre[0], p1 = (f16)hpre[1],                            \
            p2 = (f16)hpre[2], p3 = (f16)hpre[3];                            \
        union { f16 h[4]; uint2 u; } pk = {{p0, p1, p2, p3}};                \
        *(uint2*)&h_lds[PN][bb][j0] = pk.u;                                  \
    }                                                                        \
}

__global__ __launch_bounds__(512, 2) void k_scan(
    const ushort* __restrict__ gi_ws, const ushort* __restrict__ htil_ws,
    const float* __restrict__ delta_ws, const float* __restrict__ Whh,
    const float* __restrict__ bhh, float* __restrict__ Hraw)
{
    __shared__ __align__(16) char s_stage[2][SBUF];   // 52224 B
    __shared__ __align__(16) f16 h_lds[2][16][136];   //  8704 B

    const int tid  = threadIdx.x;
    const int w    = tid >> 6;          // wave 0..7: j slice [16w,16w+16); stages seq w
    const int lane = tid & 63;
    const int bb   = lane & 15;         // A row / B col / C col
    const int q    = lane >> 4;         // B k-chunk / C row group
    const bool act = bb < NB;
    const int bbw  = bb & (NB - 1);     // seq index (dup for lanes 8-15)
    const int b0   = blockIdx.x * NB;
    const int j0   = w * 16 + q * 4;    // this lane's 4 output j's
    const int wq2  = w * 32 + q * 8;    // j0 * 2 bytes (bf16)
    const int wq4  = w * 64 + q * 16;   // j0 * 4 bytes (f32)

    // Whh A-fragments: load f32, convert to f16 in-register.
    f16x8 aF[3][4];
    #pragma unroll
    for (int g = 0; g < 3; ++g) {
        const float* wr = Whh + (size_t)(g * 128 + w * 16 + bb) * 128;
        #pragma unroll
        for (int ks = 0; ks < 4; ++ks) {
            float4 a = *(const float4*)(wr + ks * 32 + q * 8);
            float4 c = *(const float4*)(wr + ks * 32 + q * 8 + 4);
            f16x8 v;
            v[0] = (f16)a.x; v[1] = (f16)a.y; v[2] = (f16)a.z; v[3] = (f16)a.w;
            v[4] = (f16)c.x; v[5] = (f16)c.y; v[6] = (f16)c.z; v[7] = (f16)c.w;
            aF[g][ks] = v;
        }
    }

    float bhn[4];
    #pragma unroll
    for (int r = 0; r < 4; ++r) bhn[r] = bhh[256 + j0 + r];

    const long rowb = (long)(b0 + bbw) * TR;
    // wave-uniform staging bases (wave w stages sequence b0+w)
    const ushort* gseq = gi_ws   + (size_t)(b0 + w) * TR * NG;
    const ushort* hseq = htil_ws + (size_t)(b0 + w) * TR * P_;
    const float*  dseq = delta_ws + (size_t)(b0 + w) * TR * P_;

    uint4 sg[TB], sd[TB];

    // ---- prologue: stage tile 0, issue tile 1 loads, init h_pre(0) ----
    STAGE_LOAD(0);
    STAGE_WRITE(s_stage[0]);        // implicit precise vmcnt before ds_write
    STAGE_LOAD(1);
    __syncthreads();

    float hpre[4];
    {
        const char* sb0 = s_stage[0];
        uint2 hh = *(const uint2*)(sb0 + bbw * GIHT_SEQ + wq2 + 768);
        float4 dd = *(const float4*)(sb0 + GIHT_SZ + bbw * DL_SEQ + wq4);
        float ht_[4] = {bflo(hh.x), bfhi(hh.x), bflo(hh.y), bfhi(hh.y)};
        float dl_[4] = {dd.x, dd.y, dd.z, dd.w};
        #pragma unroll
        for (int r = 0; r < 4; ++r)
            hpre[r] = ht_[r] - dl_[r] * ht_[r];    // h_pre(0), h(-1)=0
        f16 p0 = (f16)hpre[0], p1 = (f16)hpre[1],
            p2 = (f16)hpre[2], p3 = (f16)hpre[3];
        union { f16 h[4]; uint2 u; } pk = {{p0, p1, p2, p3}};
        *(uint2*)&h_lds[0][bb][j0] = pk.u;
    }

    // ---- main loop: 256 tiles x 2 steps ----
    int cur = 0;
    for (int tile = 0; tile < NTILE; ++tile) {
        const char* scur = s_stage[cur];
        const char* snxt = s_stage[cur ^ 1];
        const long Tg = (long)tile * TB;

        STEP(Tg, 0, scur, 1, 0, 1);
        if (tile + 1 < NTILE) STAGE_WRITE(s_stage[cur ^ 1]);
        STEP(Tg + 1, 1, snxt, 0, 1, 0);
        if (tile + 2 < NTILE) STAGE_LOAD(tile + 2);
        cur ^= 1;
    }
}

// ---------------------------------------------------------------------------
// Kernel 3: head. [unchanged]
// ---------------------------------------------------------------------------
__global__ __launch_bounds__(256) void k_head(
    const float* __restrict__ Hraw, const float* __restrict__ STD,
    const float* __restrict__ Z, const int* __restrict__ idx_map,
    const float* __restrict__ W1, const float* __restrict__ b1,
    const float* __restrict__ W2,
    float* __restrict__ eta, float* __restrict__ Hagg,
    float* __restrict__ mask_out)
{
    __shared__ float sW1[HH * FDIM];
    __shared__ float sb1[HH], sW2[HH];
    __shared__ float spart[TA][4];

    const int tid = threadIdx.x, b = blockIdx.x;
    for (int i = tid; i < HH * FDIM; i += 256) sW1[i] = W1[i];
    if (tid < HH) { sb1[tid] = b1[tid]; sW2[tid] = W2[tid]; }
    __syncthreads();

    const int s = tid >> 2, p = tid & 3;
    const int idx = idx_map[b * TA + s];
    const int valid = idx >= 0;
    const int tt = valid ? idx : 0;
    const float* hrow = Hraw + ((long)b * TR + tt) * H_;

    float acc[16];
    #pragma unroll
    for (int uu = 0; uu < 16; ++uu) acc[uu] = sb1[p * 16 + uu];

    for (int f = 0; f < FDIM; ++f) {
        float feat;
        if (f < H_)              feat = valid ? hrow[f] : 0.f;
        else if (f < H_ + PSTD)  feat = STD[((long)b * TA + s) * PSTD + (f - H_)];
        else                     feat = Z[b * PSTAT + (f - H_ - PSTD)];
        #pragma unroll
        for (int uu = 0; uu < 16; ++uu)
            acc[uu] += feat * sW1[(p * 16 + uu) * FDIM + f];
    }

    float pe = 0.f;
    #pragma unroll
    for (int uu = 0; uu < 16; ++uu) {
        float a = acc[uu];
        pe += (a > 0.f ? a : 0.f) * sW2[p * 16 + uu];
    }
    spart[s][p] = pe;

    for (int e = 0; e < 32; ++e) {
        int ee = p * 32 + e;
        Hagg[((long)b * TA + s) * H_ + ee] = valid ? hrow[ee] : 0.f;
    }
    if (p == 0) mask_out[b * TA + s] = valid ? 1.f : 0.f;

    __syncthreads();
    if (tid < TA)
        eta[b * TA + tid] = spart[tid][0] + spart[tid][1] + spart[tid][2] + spart[tid][3];
}

// ---------------------------------------------------------------------------
extern "C" void kernel_launch(void* const* d_in, const int* in_sizes, int n_in,
                              void* d_out, int out_size, void* d_ws, size_t ws_size,
                              hipStream_t stream)
{
    const float* X     = (const float*)d_in[0];
    const float* M     = (const float*)d_in[1];
    const float* DT    = (const float*)d_in[2];
    const float* STD   = (const float*)d_in[3];
    const float* Z     = (const float*)d_in[4];
    const int*   idxm  = (const int*)  d_in[5];
    const float* xmean = (const float*)d_in[6];
    const float* Wd    = (const float*)d_in[7];
    const float* bd    = (const float*)d_in[8];
    const float* Wih   = (const float*)d_in[9];
    const float* bih   = (const float*)d_in[10];
    const float* Whh   = (const float*)d_in[11];
    const float* bhh   = (const float*)d_in[12];
    const float* W1    = (const float*)d_in[13];
    const float* b1    = (const float*)d_in[14];
    const float* W2    = (const float*)d_in[15];

    const long RROWS = (long)B_ * TR;   // 131072
    char* ws = (char*)d_ws;
    size_t off = 0;
    ushort* gi_ws   = (ushort*)(ws + off); off += (size_t)RROWS * NG * 2;
    ushort* htil_ws = (ushort*)(ws + off); off += (size_t)RROWS * P_ * 2;
    float*  delta_ws= (float*) (ws + off); off += (size_t)RROWS * P_ * 4;
    ushort* wih_b   = (ushort*)(ws + off); off += (size_t)NG * KI * 2;
    ushort* wd_b    = (ushort*)(ws + off); off += (size_t)H_ * P_ * 2;
    float*  bihc    = (float*) (ws + off); off += (size_t)NG * 4;

    float* out   = (float*)d_out;
    float* eta   = out;                                  // [256,64]
    float* Hraw  = out + 16384;                          // [256,512,128]
    float* Hagg  = out + 16384 + (long)B_ * TR * H_;     // [256,64,128]
    float* maskO = Hagg + (long)B_ * TA * H_;            // [256,64]

    hipLaunchKernelGGL(k_convert, dim3(384), dim3(256), 0, stream,
                       Wih, Wd, bih, bhh, wih_b, wd_b, bihc);
    hipLaunchKernelGGL(k_gemm, dim3(2048), dim3(256), 0, stream,
                       X, M, DT, xmean, wih_b, wd_b, bihc, bd,
                       gi_ws, htil_ws, delta_ws);
    hipLaunchKernelGGL(k_scan, dim3(NSCAN), dim3(512), 0, stream,
                       gi_ws, htil_ws, delta_ws, Whh, bhh, Hraw);
    hipLaunchKernelGGL(k_head, dim3(256), dim3(256), 0, stream,
                       Hraw, STD, Z, idxm, W1, b1, W2, eta, Hagg, maskO);
}

// Round 7
// 740.396 us; speedup vs baseline: 1.7859x; 1.7859x over previous
//
#include <hip/hip_runtime.h>
#include <hip/hip_bf16.h>
#include <hip/hip_fp16.h>

// Problem constants
#define B_    256
#define TR    512
#define P_    128
#define H_    128
#define NG    384      // 3*H
#define KI    256      // 2*P
#define TA    64
#define PSTD  32
#define PSTAT 16
#define HH    64       // HEAD_H
#define FDIM  176      // H + P_STD + P_STATIC

#define TB    16       // scan time-tile (LDS-resident steps)
#define NT    (TR/TB)  // 32 tiles
#define TILE_BYTES 24576   // gi(12288) + htil(4096) + delta(8192) per tile

typedef __attribute__((ext_vector_type(8))) short short8;
typedef __attribute__((ext_vector_type(4))) float f32x4;
typedef _Float16 f16;
typedef __attribute__((ext_vector_type(2))) _Float16 f16x2;

// ---- helpers ----
__device__ __forceinline__ float bf2f(ushort u) {
    union { uint i; float f; } v; v.i = ((uint)u) << 16; return v.f;
}
__device__ __forceinline__ ushort f2bf(float f) {
    union { float f; uint u; } v; v.f = f;
    uint u = v.u;
    uint r = (u + 0x7fffu + ((u >> 16) & 1u)) >> 16;  // RTNE
    return (ushort)r;
}
__device__ __forceinline__ float sigf(float x) {
    return 1.f / (1.f + __expf(-x));
}
__device__ __forceinline__ float tanhf_fast(float x) {
    float ax = fabsf(x);
    float e = __expf(-2.f * ax);          // underflows to 0 for large ax -> r=1
    float r = (1.f - e) / (1.f + e);
    return copysignf(r, x);
}
// LDS-only barrier: does NOT drain vmcnt beyond what the baseline did.
__device__ __forceinline__ void bar_lds() {
    __asm__ volatile("s_waitcnt lgkmcnt(0)\n\ts_barrier" ::: "memory");
}
// DPP quad-perm adds
__device__ __forceinline__ float dpp_add_xor1(float x) {
    int r = __builtin_amdgcn_mov_dpp(__float_as_int(x), 0xB1, 0xF, 0xF, true);
    return x + __int_as_float(r);
}
__device__ __forceinline__ float dpp_add_xor2(float x) {
    int r = __builtin_amdgcn_mov_dpp(__float_as_int(x), 0x4E, 0xF, 0xF, true);
    return x + __int_as_float(r);
}

// ---------------------------------------------------------------------------
// Kernel 0: convert Wih, Wd to bf16  [round-0 baseline]
// ---------------------------------------------------------------------------
__global__ __launch_bounds__(256) void k_convert(
    const float* __restrict__ Wih, const float* __restrict__ Wd,
    ushort* __restrict__ wih_b, ushort* __restrict__ wd_b)
{
    int i = blockIdx.x * 256 + threadIdx.x;
    if (i < NG * KI) wih_b[i] = f2bf(Wih[i]);
    if (i < H_ * P_) wd_b[i]  = f2bf(Wd[i]);
}

// ---------------------------------------------------------------------------
// Kernel 1: fused elementwise + GEMM (MFMA bf16 16x16x32). [round-0 baseline]
// ---------------------------------------------------------------------------
#define SA 392   // padded LDS row stride in bf16 elems (also >= 384 for staging)

__global__ __launch_bounds__(256, 2) void k_gemm(
    const float* __restrict__ X, const float* __restrict__ M,
    const float* __restrict__ DT, const float* __restrict__ xmean,
    const ushort* __restrict__ wih_b, const ushort* __restrict__ wd_b,
    const float* __restrict__ bih, const float* __restrict__ bd,
    ushort* __restrict__ gi_ws, ushort* __restrict__ htil_ws,
    float* __restrict__ delta_ws)
{
    __shared__ __align__(16) ushort sA[64 * SA];   // 50176 B; reused for staging
    const int tid = threadIdx.x;
    const long r0 = (long)blockIdx.x * 64;

    // ---- build A tile (64 rows x [x_dec|m|x_hat]) + delta (coalesced f32) ----
    #pragma unroll 4
    for (int i = 0; i < 32; ++i) {
        int idx = i * 256 + tid;
        int rl = idx >> 7, k = idx & 127;
        long g = (r0 + rl) * 128 + k;
        float x = X[g], m = M[g], dt = DT[g], xm = xmean[k];
        float delta = 1.f / (1.f + __expf(dt));   // sigmoid(-dt)
        float xh = m * x + (1.f - m) * xm;
        float xd = m * x + (1.f - m) * (delta * xh + (1.f - delta) * xm);
        sA[rl * SA + k]       = f2bf(xd);
        sA[rl * SA + 128 + k] = f2bf(m);
        sA[rl * SA + 256 + k] = f2bf(xh);
        delta_ws[g] = delta;
    }
    __syncthreads();

    const int wv   = tid >> 6;        // wave 0..3 -> gi col slice [96w,96w+96)
    const int lane = tid & 63;
    const int l16  = lane & 15;       // A row idx / B col idx / C col idx
    const int q    = lane >> 4;       // quad: A k-offset q*8 / C rows q*4+reg

    // ---- gi: acc[rt][nt], rt = row-tile (16 rows), nt = col-tile in slice ----
    f32x4 acc[4][6];
    #pragma unroll
    for (int rt = 0; rt < 4; ++rt)
        #pragma unroll
        for (int nt = 0; nt < 6; ++nt) acc[rt][nt] = (f32x4){0.f, 0.f, 0.f, 0.f};

    const int nb = 96 * wv;
    #pragma unroll
    for (int ks = 0; ks < 8; ++ks) {
        short8 a[4];
        #pragma unroll
        for (int rt = 0; rt < 4; ++rt)
            a[rt] = *(const short8*)&sA[(rt * 16 + l16) * SA + ks * 32 + q * 8];
        #pragma unroll
        for (int nt = 0; nt < 6; ++nt) {
            const short8 b = *(const short8*)&wih_b[(size_t)(nb + nt * 16 + l16) * KI + ks * 32 + q * 8];
            #pragma unroll
            for (int rt = 0; rt < 4; ++rt)
                acc[rt][nt] = __builtin_amdgcn_mfma_f32_16x16x32_bf16(a[rt], b, acc[rt][nt], 0, 0, 0);
        }
    }

    // ---- htil: acc2[rt][nt2], col slice [32w,32w+32), K=128 (A cols 256+) ----
    f32x4 acc2[4][2];
    #pragma unroll
    for (int rt = 0; rt < 4; ++rt)
        #pragma unroll
        for (int nt = 0; nt < 2; ++nt) acc2[rt][nt] = (f32x4){0.f, 0.f, 0.f, 0.f};

    const int nb2 = 32 * wv;
    #pragma unroll
    for (int ks = 0; ks < 4; ++ks) {
        short8 a[4];
        #pragma unroll
        for (int rt = 0; rt < 4; ++rt)
            a[rt] = *(const short8*)&sA[(rt * 16 + l16) * SA + 256 + ks * 32 + q * 8];
        #pragma unroll
        for (int nt = 0; nt < 2; ++nt) {
            const short8 b = *(const short8*)&wd_b[(size_t)(nb2 + nt * 16 + l16) * P_ + ks * 32 + q * 8];
            #pragma unroll
            for (int rt = 0; rt < 4; ++rt)
                acc2[rt][nt] = __builtin_amdgcn_mfma_f32_16x16x32_bf16(a[rt], b, acc2[rt][nt], 0, 0, 0);
        }
    }

    __syncthreads();   // all sA reads done; safe to overwrite with staging

    // ---- stage gi (bf16, [row][n] unpadded 64x384) into sA region ----
    ushort* sOut = sA;
    #pragma unroll
    for (int nt = 0; nt < 6; ++nt) {
        const int n = nb + nt * 16 + l16;
        const float bi = bih[n];
        #pragma unroll
        for (int rt = 0; rt < 4; ++rt) {
            #pragma unroll
            for (int reg = 0; reg < 4; ++reg) {
                int row = rt * 16 + q * 4 + reg;
                sOut[row * NG + n] = f2bf(acc[rt][nt][reg] + bi);
            }
        }
    }
    __syncthreads();

    // ---- coalesced contiguous store: 64*384 bf16 = 3072 uint4 ----
    {
        uint4* dst = (uint4*)(gi_ws + (size_t)r0 * NG);
        const uint4* src = (const uint4*)sOut;
        #pragma unroll
        for (int i = 0; i < 12; ++i) dst[tid + 256 * i] = src[tid + 256 * i];
    }
    __syncthreads();   // uint4 LDS reads retired; safe to restage

    // ---- stage htil (bf16, [row][n] 64x128) ----
    #pragma unroll
    for (int nt = 0; nt < 2; ++nt) {
        const int n = nb2 + nt * 16 + l16;
        const float bi = bd[n];
        #pragma unroll
        for (int rt = 0; rt < 4; ++rt) {
            #pragma unroll
            for (int reg = 0; reg < 4; ++reg) {
                int row = rt * 16 + q * 4 + reg;
                sOut[row * P_ + n] = f2bf(tanhf_fast(acc2[rt][nt][reg] + bi));
            }
        }
    }
    __syncthreads();

    // ---- coalesced store: 64*128 bf16 = 1024 uint4 ----
    {
        uint4* dst = (uint4*)(htil_ws + (size_t)r0 * P_);
        const uint4* src = (const uint4*)sOut;
        #pragma unroll
        for (int i = 0; i < 4; ++i) dst[tid + 256 * i] = src[tid + 256 * i];
    }
}

// ---------------------------------------------------------------------------
// Kernel 2: recurrent scan v9 — round-0 baseline structure (the only one
//   that has performed: 431us), with ONE change: the h-matvec inner product
//   uses packed-f16 v_dot2_f32_f16 (fdot2) instead of f32 fma.
//   - wh[3][16] packed f16 pairs (48 VGPR, was 96 as float4)
//   - s_hpre stored as packed f16 pair-words, per-q 20-word sections:
//     reader = 4 ds_read_b128 (was 8), banks {0-3,20-23,8-11,28-31},
//     same-q lanes broadcast -> conflict-free
//   - inner loop = 48 fdot2 (was 96 v_fma)
//   Everything else (tile staging, barriers, DPP reduce, epilogue) verbatim.
//   f16 weights + f16 h already numerically validated (rounds 2-6, absmax
//   0.0067 unchanged vs f32 baseline).
// ---------------------------------------------------------------------------
__global__ __launch_bounds__(512, 2) void k_scan(
    const ushort* __restrict__ gi_ws, const ushort* __restrict__ htil_ws,
    const float* __restrict__ delta_ws, const float* __restrict__ Whh,
    const float* __restrict__ bhh, float* __restrict__ Hraw)
{
    __shared__ __align__(16) char  s_in[2][TILE_BYTES];  // 49152 B
    __shared__ __align__(16) float s_hout[TB * P_];      //  8192 B
    __shared__ __align__(16) uint  s_hp16[2][80];        //   640 B packed f16

    const int tid = threadIdx.x;
    const int b   = blockIdx.x;
    const int j   = tid >> 2;
    const int q   = tid & 3;
    const long base = (long)b * TR;

    // packed f16 weights: wh[g][i] covers k = q*32 + 2i, 2i+1
    f16x2 wh[3][16];
    #pragma unroll
    for (int g = 0; g < 3; ++g) {
        const float* wp = Whh + ((g << 7) + j) * H_ + (q << 5);
        #pragma unroll
        for (int i = 0; i < 16; ++i) {
            f16x2 v;
            v[0] = (f16)wp[2 * i];
            v[1] = (f16)wp[2 * i + 1];
            wh[g][i] = v;
        }
    }
    float bh0 = 0.f, bh1 = 0.f, bh2 = 0.f;
    if (q == 0) { bh0 = bhh[j]; bh1 = bhh[128 + j]; bh2 = bhh[256 + j]; }

    {
        const uint4* gi4 = (const uint4*)(gi_ws   + (size_t)base * NG);
        const uint4* ht4 = (const uint4*)(htil_ws + (size_t)base * P_);
        const uint4* dl4 = (const uint4*)(delta_ws + (size_t)base * P_);
        uint4 p0 = gi4[tid];
        uint4 p1 = (tid < 256) ? gi4[512 + tid] : ht4[tid - 256];
        uint4 p2 = dl4[tid];
        uint4* d = (uint4*)s_in[0];
        d[tid] = p0; d[512 + tid] = p1; d[1024 + tid] = p2;
    }
    bar_lds();

    // h_pre store position: pair-word = (j>>5)*20 + ((j&31)>>1), half = j&1
    const int wpos = ((j >> 5) * 20 + ((j & 31) >> 1)) * 2 + (j & 1);

    int cur = 0, sb = 0;
    float h = 0.f, h_pre = 0.f;
    float d_c = 0.f, ht_c = 0.f, gr_c = 0.f, gz_c = 0.f, gn_c = 0.f;

    for (int tile = 0; tile < NT; ++tile) {
        uint4 p0, p1, p2;
        const int has_next = (tile + 1 < NT);
        if (has_next) {
            const long tn = base + (long)(tile + 1) * TB;
            const uint4* gi4 = (const uint4*)(gi_ws   + (size_t)tn * NG);
            const uint4* ht4 = (const uint4*)(htil_ws + (size_t)tn * P_);
            const uint4* dl4 = (const uint4*)(delta_ws + (size_t)tn * P_);
            p0 = gi4[tid];
            p1 = (tid < 256) ? gi4[512 + tid] : ht4[tid - 256];
            p2 = dl4[tid];
        }

        const ushort* sgi = (const ushort*)s_in[cur];
        const ushort* sht = (const ushort*)(s_in[cur] + 12288);
        const float*  sdl = (const float*) (s_in[cur] + 16384);

        if (q == 0) {
            d_c  = sdl[j];
            ht_c = bf2f(sht[j]);
            gr_c = bf2f(sgi[j]);
            gz_c = bf2f(sgi[128 + j]);
            gn_c = bf2f(sgi[256 + j]);
        }

        for (int ts = 0; ts < TB; ++ts) {
            if (q == 0) {
                h_pre = d_c * h + (1.f - d_c) * ht_c;
                ((f16*)s_hp16[sb])[wpos] = (f16)h_pre;
            }
            bar_lds();

            float d_n = d_c, ht_n = ht_c, gr_n = gr_c, gz_n = gz_c, gn_n = gn_c;
            if (q == 0 && ts + 1 < TB) {
                d_n  = sdl[(ts + 1) * P_ + j];
                ht_n = bf2f(sht[(ts + 1) * P_ + j]);
                gr_n = bf2f(sgi[(ts + 1) * NG + j]);
                gz_n = bf2f(sgi[(ts + 1) * NG + 128 + j]);
                gn_n = bf2f(sgi[(ts + 1) * NG + 256 + j]);
            }

            // 4 x ds_read_b128 of packed f16 h_pre; 48 fdot2
            const uint4* hp = (const uint4*)&s_hp16[sb][q * 20];
            float ar0 = 0.f, ar1 = 0.f, az0 = 0.f, az1 = 0.f, an0 = 0.f, an1 = 0.f;
            #pragma unroll
            for (int i = 0; i < 4; ++i) {
                uint4 hv4 = hp[i];
                uint wds[4] = {hv4.x, hv4.y, hv4.z, hv4.w};
                #pragma unroll
                for (int k2 = 0; k2 < 4; ++k2) {
                    union { uint u; f16x2 h; } cv; cv.u = wds[k2];
                    const int ii = i * 4 + k2;
                    if (ii & 1) {
                        ar1 = __builtin_amdgcn_fdot2(cv.h, wh[0][ii], ar1, false);
                        az1 = __builtin_amdgcn_fdot2(cv.h, wh[1][ii], az1, false);
                        an1 = __builtin_amdgcn_fdot2(cv.h, wh[2][ii], an1, false);
                    } else {
                        ar0 = __builtin_amdgcn_fdot2(cv.h, wh[0][ii], ar0, false);
                        az0 = __builtin_amdgcn_fdot2(cv.h, wh[1][ii], az0, false);
                        an0 = __builtin_amdgcn_fdot2(cv.h, wh[2][ii], an0, false);
                    }
                }
            }
            float sr = ar0 + ar1, sz = az0 + az1, sn = an0 + an1;
            sr = dpp_add_xor2(dpp_add_xor1(sr));
            sz = dpp_add_xor2(dpp_add_xor1(sz));
            sn = dpp_add_xor2(dpp_add_xor1(sn));

            if (q == 0) {
                float r = sigf(gr_c + bh0 + sr);
                float z = sigf(gz_c + bh1 + sz);
                float n = tanhf_fast(gn_c + r * (bh2 + sn));
                h = (1.f - z) * n + z * h_pre;
                s_hout[ts * P_ + j] = h;
                d_c = d_n; ht_c = ht_n; gr_c = gr_n; gz_c = gz_n; gn_c = gn_n;
            }
            sb ^= 1;
        }

        bar_lds();

        {
            uint4* dst = (uint4*)(Hraw + (base + (long)tile * TB) * H_);
            dst[tid] = ((const uint4*)s_hout)[tid];
        }
        if (has_next) {
            uint4* d = (uint4*)s_in[cur ^ 1];
            d[tid] = p0; d[512 + tid] = p1; d[1024 + tid] = p2;
        }
        bar_lds();
        cur ^= 1;
    }
}

// ---------------------------------------------------------------------------
// Kernel 3: head. [unchanged]
// ---------------------------------------------------------------------------
__global__ __launch_bounds__(256) void k_head(
    const float* __restrict__ Hraw, const float* __restrict__ STD,
    const float* __restrict__ Z, const int* __restrict__ idx_map,
    const float* __restrict__ W1, const float* __restrict__ b1,
    const float* __restrict__ W2,
    float* __restrict__ eta, float* __restrict__ Hagg,
    float* __restrict__ mask_out)
{
    __shared__ float sW1[HH * FDIM];
    __shared__ float sb1[HH], sW2[HH];
    __shared__ float spart[TA][4];

    const int tid = threadIdx.x, b = blockIdx.x;
    for (int i = tid; i < HH * FDIM; i += 256) sW1[i] = W1[i];
    if (tid < HH) { sb1[tid] = b1[tid]; sW2[tid] = W2[tid]; }
    __syncthreads();

    const int s = tid >> 2, p = tid & 3;
    const int idx = idx_map[b * TA + s];
    const int valid = idx >= 0;
    const int tt = valid ? idx : 0;
    const float* hrow = Hraw + ((long)b * TR + tt) * H_;

    float acc[16];
    #pragma unroll
    for (int uu = 0; uu < 16; ++uu) acc[uu] = sb1[p * 16 + uu];

    for (int f = 0; f < FDIM; ++f) {
        float feat;
        if (f < H_)              feat = valid ? hrow[f] : 0.f;
        else if (f < H_ + PSTD)  feat = STD[((long)b * TA + s) * PSTD + (f - H_)];
        else                     feat = Z[b * PSTAT + (f - H_ - PSTD)];
        #pragma unroll
        for (int uu = 0; uu < 16; ++uu)
            acc[uu] += feat * sW1[(p * 16 + uu) * FDIM + f];
    }

    float pe = 0.f;
    #pragma unroll
    for (int uu = 0; uu < 16; ++uu) {
        float a = acc[uu];
        pe += (a > 0.f ? a : 0.f) * sW2[p * 16 + uu];
    }
    spart[s][p] = pe;

    for (int e = 0; e < 32; ++e) {
        int ee = p * 32 + e;
        Hagg[((long)b * TA + s) * H_ + ee] = valid ? hrow[ee] : 0.f;
    }
    if (p == 0) mask_out[b * TA + s] = valid ? 1.f : 0.f;

    __syncthreads();
    if (tid < TA)
        eta[b * TA + tid] = spart[tid][0] + spart[tid][1] + spart[tid][2] + spart[tid][3];
}

// ---------------------------------------------------------------------------
extern "C" void kernel_launch(void* const* d_in, const int* in_sizes, int n_in,
                              void* d_out, int out_size, void* d_ws, size_t ws_size,
                              hipStream_t stream)
{
    const float* X     = (const float*)d_in[0];
    const float* M     = (const float*)d_in[1];
    const float* DT    = (const float*)d_in[2];
    const float* STD   = (const float*)d_in[3];
    const float* Z     = (const float*)d_in[4];
    const int*   idxm  = (const int*)  d_in[5];
    const float* xmean = (const float*)d_in[6];
    const float* Wd    = (const float*)d_in[7];
    const float* bd    = (const float*)d_in[8];
    const float* Wih   = (const float*)d_in[9];
    const float* bih   = (const float*)d_in[10];
    const float* Whh   = (const float*)d_in[11];
    const float* bhh   = (const float*)d_in[12];
    const float* W1    = (const float*)d_in[13];
    const float* b1    = (const float*)d_in[14];
    const float* W2    = (const float*)d_in[15];

    const long RROWS = (long)B_ * TR;   // 131072
    char* ws = (char*)d_ws;
    size_t off = 0;
    ushort* gi_ws   = (ushort*)(ws + off); off += (size_t)RROWS * NG * 2;
    ushort* htil_ws = (ushort*)(ws + off); off += (size_t)RROWS * P_ * 2;
    float*  delta_ws= (float*) (ws + off); off += (size_t)RROWS * P_ * 4;
    ushort* wih_b   = (ushort*)(ws + off); off += (size_t)NG * KI * 2;
    ushort* wd_b    = (ushort*)(ws + off); off += (size_t)H_ * P_ * 2;

    float* out   = (float*)d_out;
    float* eta   = out;                                  // [256,64]
    float* Hraw  = out + 16384;                          // [256,512,128]
    float* Hagg  = out + 16384 + (long)B_ * TR * H_;     // [256,64,128]
    float* maskO = Hagg + (long)B_ * TA * H_;            // [256,64]

    hipLaunchKernelGGL(k_convert, dim3(384), dim3(256), 0, stream,
                       Wih, Wd, wih_b, wd_b);
    hipLaunchKernelGGL(k_gemm, dim3(2048), dim3(256), 0, stream,
                       X, M, DT, xmean, wih_b, wd_b, bih, bd,
                       gi_ws, htil_ws, delta_ws);
    hipLaunchKernelGGL(k_scan, dim3(256), dim3(512), 0, stream,
                       gi_ws, htil_ws, delta_ws, Whh, bhh, Hraw);
    hipLaunchKernelGGL(k_head, dim3(256), dim3(256), 0, stream,
                       Hraw, STD, Z, idxm, W1, b1, W2, eta, Hagg, maskO);
}

// Round 8
// 689.790 us; speedup vs baseline: 1.9169x; 1.0734x over previous
//
#include <hip/hip_runtime.h>
#include <hip/hip_bf16.h>
#include <hip/hip_fp16.h>

// Problem constants
#define B_    256
#define TR    512
#define P_    128
#define H_    128
#define NG    384      // 3*H
#define KI    256      // 2*P
#define TA    64
#define PSTD  32
#define PSTAT 16
#define HH    64       // HEAD_H
#define FDIM  176      // H + P_STD + P_STATIC

#define TB    16       // scan time-tile (LDS-resident steps)
#define NT    (TR/TB)  // 32 tiles
#define TILE_BYTES 24576   // gi(12288) + htil(4096) + delta(8192) per tile

typedef __attribute__((ext_vector_type(8))) short short8;
typedef __attribute__((ext_vector_type(4))) float f32x4;
typedef _Float16 f16;
typedef __attribute__((ext_vector_type(2))) _Float16 f16x2;

// ---- helpers ----
__device__ __forceinline__ float bf2f(ushort u) {
    union { uint i; float f; } v; v.i = ((uint)u) << 16; return v.f;
}
__device__ __forceinline__ ushort f2bf(float f) {
    union { float f; uint u; } v; v.f = f;
    uint u = v.u;
    uint r = (u + 0x7fffu + ((u >> 16) & 1u)) >> 16;  // RTNE
    return (ushort)r;
}
__device__ __forceinline__ float sigf(float x) {
    return 1.f / (1.f + __expf(-x));
}
__device__ __forceinline__ float tanhf_fast(float x) {
    float ax = fabsf(x);
    float e = __expf(-2.f * ax);          // underflows to 0 for large ax -> r=1
    float r = (1.f - e) / (1.f + e);
    return copysignf(r, x);
}
// branch-free scan transcendentals (v_exp + v_rcp; validated rounds 2-6,
// absmax 0.006713 — replaces the ~10-instr v_div_* sequence on the chain)
__device__ __forceinline__ float sigf2(float x) {
    return __builtin_amdgcn_rcpf(1.f + __expf(-x));
}
__device__ __forceinline__ float tanh2(float x) {
    // tanh(x) = 1 - 2/(exp(2x)+1); saturates correctly, no NaN
    return 1.f - 2.f * __builtin_amdgcn_rcpf(1.f + __expf(2.f * x));
}
// LDS-only barrier WITHOUT a memory clobber: no forced vmcnt drain.
// sched_barrier(0) fences pin ds_write -> lgkmcnt(0) -> s_barrier ordering
// and stop LDS reads from hoisting above the barrier (v6-validated form).
__device__ __forceinline__ void bar_lds() {
    __builtin_amdgcn_sched_barrier(0);
    __asm__ volatile("s_waitcnt lgkmcnt(0)");
    __builtin_amdgcn_s_barrier();
    __builtin_amdgcn_sched_barrier(0);
}
// DPP quad-perm adds (after xor1+xor2 ALL 4 quad lanes hold the full sum)
__device__ __forceinline__ float dpp_add_xor1(float x) {
    int r = __builtin_amdgcn_mov_dpp(__float_as_int(x), 0xB1, 0xF, 0xF, true);
    return x + __int_as_float(r);
}
__device__ __forceinline__ float dpp_add_xor2(float x) {
    int r = __builtin_amdgcn_mov_dpp(__float_as_int(x), 0x4E, 0xF, 0xF, true);
    return x + __int_as_float(r);
}

// ---------------------------------------------------------------------------
// Kernel 0: convert Wih, Wd to bf16  [unchanged]
// ---------------------------------------------------------------------------
__global__ __launch_bounds__(256) void k_convert(
    const float* __restrict__ Wih, const float* __restrict__ Wd,
    ushort* __restrict__ wih_b, ushort* __restrict__ wd_b)
{
    int i = blockIdx.x * 256 + threadIdx.x;
    if (i < NG * KI) wih_b[i] = f2bf(Wih[i]);
    if (i < H_ * P_) wd_b[i]  = f2bf(Wd[i]);
}

// ---------------------------------------------------------------------------
// Kernel 1: fused elementwise + GEMM (MFMA bf16 16x16x32). [unchanged]
// ---------------------------------------------------------------------------
#define SA 392   // padded LDS row stride in bf16 elems (also >= 384 for staging)

__global__ __launch_bounds__(256, 2) void k_gemm(
    const float* __restrict__ X, const float* __restrict__ M,
    const float* __restrict__ DT, const float* __restrict__ xmean,
    const ushort* __restrict__ wih_b, const ushort* __restrict__ wd_b,
    const float* __restrict__ bih, const float* __restrict__ bd,
    ushort* __restrict__ gi_ws, ushort* __restrict__ htil_ws,
    float* __restrict__ delta_ws)
{
    __shared__ __align__(16) ushort sA[64 * SA];   // 50176 B; reused for staging
    const int tid = threadIdx.x;
    const long r0 = (long)blockIdx.x * 64;

    // ---- build A tile (64 rows x [x_dec|m|x_hat]) + delta (coalesced f32) ----
    #pragma unroll 4
    for (int i = 0; i < 32; ++i) {
        int idx = i * 256 + tid;
        int rl = idx >> 7, k = idx & 127;
        long g = (r0 + rl) * 128 + k;
        float x = X[g], m = M[g], dt = DT[g], xm = xmean[k];
        float delta = 1.f / (1.f + __expf(dt));   // sigmoid(-dt)
        float xh = m * x + (1.f - m) * xm;
        float xd = m * x + (1.f - m) * (delta * xh + (1.f - delta) * xm);
        sA[rl * SA + k]       = f2bf(xd);
        sA[rl * SA + 128 + k] = f2bf(m);
        sA[rl * SA + 256 + k] = f2bf(xh);
        delta_ws[g] = delta;
    }
    __syncthreads();

    const int wv   = tid >> 6;        // wave 0..3 -> gi col slice [96w,96w+96)
    const int lane = tid & 63;
    const int l16  = lane & 15;       // A row idx / B col idx / C col idx
    const int q    = lane >> 4;       // quad: A k-offset q*8 / C rows q*4+reg

    // ---- gi: acc[rt][nt], rt = row-tile (16 rows), nt = col-tile in slice ----
    f32x4 acc[4][6];
    #pragma unroll
    for (int rt = 0; rt < 4; ++rt)
        #pragma unroll
        for (int nt = 0; nt < 6; ++nt) acc[rt][nt] = (f32x4){0.f, 0.f, 0.f, 0.f};

    const int nb = 96 * wv;
    #pragma unroll
    for (int ks = 0; ks < 8; ++ks) {
        short8 a[4];
        #pragma unroll
        for (int rt = 0; rt < 4; ++rt)
            a[rt] = *(const short8*)&sA[(rt * 16 + l16) * SA + ks * 32 + q * 8];
        #pragma unroll
        for (int nt = 0; nt < 6; ++nt) {
            const short8 b = *(const short8*)&wih_b[(size_t)(nb + nt * 16 + l16) * KI + ks * 32 + q * 8];
            #pragma unroll
            for (int rt = 0; rt < 4; ++rt)
                acc[rt][nt] = __builtin_amdgcn_mfma_f32_16x16x32_bf16(a[rt], b, acc[rt][nt], 0, 0, 0);
        }
    }

    // ---- htil: acc2[rt][nt2], col slice [32w,32w+32), K=128 (A cols 256+) ----
    f32x4 acc2[4][2];
    #pragma unroll
    for (int rt = 0; rt < 4; ++rt)
        #pragma unroll
        for (int nt = 0; nt < 2; ++nt) acc2[rt][nt] = (f32x4){0.f, 0.f, 0.f, 0.f};

    const int nb2 = 32 * wv;
    #pragma unroll
    for (int ks = 0; ks < 4; ++ks) {
        short8 a[4];
        #pragma unroll
        for (int rt = 0; rt < 4; ++rt)
            a[rt] = *(const short8*)&sA[(rt * 16 + l16) * SA + 256 + ks * 32 + q * 8];
        #pragma unroll
        for (int nt = 0; nt < 2; ++nt) {
            const short8 b = *(const short8*)&wd_b[(size_t)(nb2 + nt * 16 + l16) * P_ + ks * 32 + q * 8];
            #pragma unroll
            for (int rt = 0; rt < 4; ++rt)
                acc2[rt][nt] = __builtin_amdgcn_mfma_f32_16x16x32_bf16(a[rt], b, acc2[rt][nt], 0, 0, 0);
        }
    }

    __syncthreads();   // all sA reads done; safe to overwrite with staging

    // ---- stage gi (bf16, [row][n] unpadded 64x384) into sA region ----
    ushort* sOut = sA;
    #pragma unroll
    for (int nt = 0; nt < 6; ++nt) {
        const int n = nb + nt * 16 + l16;
        const float bi = bih[n];
        #pragma unroll
        for (int rt = 0; rt < 4; ++rt) {
            #pragma unroll
            for (int reg = 0; reg < 4; ++reg) {
                int row = rt * 16 + q * 4 + reg;
                sOut[row * NG + n] = f2bf(acc[rt][nt][reg] + bi);
            }
        }
    }
    __syncthreads();

    // ---- coalesced contiguous store: 64*384 bf16 = 3072 uint4 ----
    {
        uint4* dst = (uint4*)(gi_ws + (size_t)r0 * NG);
        const uint4* src = (const uint4*)sOut;
        #pragma unroll
        for (int i = 0; i < 12; ++i) dst[tid + 256 * i] = src[tid + 256 * i];
    }
    __syncthreads();   // uint4 LDS reads retired; safe to restage

    // ---- stage htil (bf16, [row][n] 64x128) ----
    #pragma unroll
    for (int nt = 0; nt < 2; ++nt) {
        const int n = nb2 + nt * 16 + l16;
        const float bi = bd[n];
        #pragma unroll
        for (int rt = 0; rt < 4; ++rt) {
            #pragma unroll
            for (int reg = 0; reg < 4; ++reg) {
                int row = rt * 16 + q * 4 + reg;
                sOut[row * P_ + n] = f2bf(tanhf_fast(acc2[rt][nt][reg] + bi));
            }
        }
    }
    __syncthreads();

    // ---- coalesced store: 64*128 bf16 = 1024 uint4 ----
    {
        uint4* dst = (uint4*)(htil_ws + (size_t)r0 * P_);
        const uint4* src = (const uint4*)sOut;
        #pragma unroll
        for (int i = 0; i < 4; ++i) dst[tid + 256 * i] = src[tid + 256 * i];
    }
}

// ---------------------------------------------------------------------------
// Kernel 2: recurrent scan v10 — v9 (384us, WIN) + four chain-shortening
//   changes, same skeleton:
//   1. rcpf-based sigf2/tanh2 (drops 2 v_div_* sequences off the chain)
//   2. branch-free epilogue: DPP xor1+xor2 leaves full sums in all 4 quad
//      lanes -> all lanes compute gates/h redundantly (LDS broadcast reads,
//      bit-identical per quad); only stores stay q==0-guarded
//   3. s_hout removed: q==0 stores h directly to Hraw (16 lanes/wave write
//      64B contiguous segments); kills one barrier/tile + 8KB LDS traffic
//   4. non-clobber bar_lds (no forced per-step vmcnt drain; staging ds_write
//      keeps its precise data-dep vmcnt once per tile)
// ---------------------------------------------------------------------------
__global__ __launch_bounds__(512, 2) void k_scan(
    const ushort* __restrict__ gi_ws, const ushort* __restrict__ htil_ws,
    const float* __restrict__ delta_ws, const float* __restrict__ Whh,
    const float* __restrict__ bhh, float* __restrict__ Hraw)
{
    __shared__ __align__(16) char  s_in[2][TILE_BYTES];  // 49152 B
    __shared__ __align__(16) uint  s_hp16[2][80];        //   640 B packed f16

    const int tid = threadIdx.x;
    const int b   = blockIdx.x;
    const int j   = tid >> 2;
    const int q   = tid & 3;
    const long base = (long)b * TR;

    // packed f16 weights: wh[g][i] covers k = q*32 + 2i, 2i+1
    f16x2 wh[3][16];
    #pragma unroll
    for (int g = 0; g < 3; ++g) {
        const float* wp = Whh + ((g << 7) + j) * H_ + (q << 5);
        #pragma unroll
        for (int i = 0; i < 16; ++i) {
            f16x2 v;
            v[0] = (f16)wp[2 * i];
            v[1] = (f16)wp[2 * i + 1];
            wh[g][i] = v;
        }
    }
    // all lanes load biases (4 lanes/quad hit same address)
    const float bh0 = bhh[j], bh1 = bhh[128 + j], bh2 = bhh[256 + j];

    {
        const uint4* gi4 = (const uint4*)(gi_ws   + (size_t)base * NG);
        const uint4* ht4 = (const uint4*)(htil_ws + (size_t)base * P_);
        const uint4* dl4 = (const uint4*)(delta_ws + (size_t)base * P_);
        uint4 p0 = gi4[tid];
        uint4 p1 = (tid < 256) ? gi4[512 + tid] : ht4[tid - 256];
        uint4 p2 = dl4[tid];
        uint4* d = (uint4*)s_in[0];
        d[tid] = p0; d[512 + tid] = p1; d[1024 + tid] = p2;
    }
    bar_lds();

    // h_pre store position: pair-word = (j>>5)*20 + ((j&31)>>1), half = j&1
    const int wpos = ((j >> 5) * 20 + ((j & 31) >> 1)) * 2 + (j & 1);

    int cur = 0, sb = 0;
    float h = 0.f;

    for (int tile = 0; tile < NT; ++tile) {
        uint4 p0, p1, p2;
        const int has_next = (tile + 1 < NT);
        if (has_next) {
            const long tn = base + (long)(tile + 1) * TB;
            const uint4* gi4 = (const uint4*)(gi_ws   + (size_t)tn * NG);
            const uint4* ht4 = (const uint4*)(htil_ws + (size_t)tn * P_);
            const uint4* dl4 = (const uint4*)(delta_ws + (size_t)tn * P_);
            p0 = gi4[tid];
            p1 = (tid < 256) ? gi4[512 + tid] : ht4[tid - 256];
            p2 = dl4[tid];
        }

        const ushort* sgi = (const ushort*)s_in[cur];
        const ushort* sht = (const ushort*)(s_in[cur] + 12288);
        const float*  sdl = (const float*) (s_in[cur] + 16384);

        // gate values for step 0 (all lanes; quad-broadcast reads)
        float d_c  = sdl[j];
        float ht_c = bf2f(sht[j]);
        float gr_c = bf2f(sgi[j]);
        float gz_c = bf2f(sgi[128 + j]);
        float gn_c = bf2f(sgi[256 + j]);

        for (int ts = 0; ts < TB; ++ts) {
            // h_pre: all lanes (bit-identical per quad); write by q==0
            float h_pre = d_c * h + (1.f - d_c) * ht_c;
            if (q == 0)
                ((f16*)s_hp16[sb])[wpos] = (f16)h_pre;
            bar_lds();

            // prefetch next step's gates (all lanes)
            float d_n = d_c, ht_n = ht_c, gr_n = gr_c, gz_n = gz_c, gn_n = gn_c;
            if (ts + 1 < TB) {
                d_n  = sdl[(ts + 1) * P_ + j];
                ht_n = bf2f(sht[(ts + 1) * P_ + j]);
                gr_n = bf2f(sgi[(ts + 1) * NG + j]);
                gz_n = bf2f(sgi[(ts + 1) * NG + 128 + j]);
                gn_n = bf2f(sgi[(ts + 1) * NG + 256 + j]);
            }

            // 4 x ds_read_b128 of packed f16 h_pre; 48 fdot2
            const uint4* hp = (const uint4*)&s_hp16[sb][q * 20];
            float ar0 = 0.f, ar1 = 0.f, az0 = 0.f, az1 = 0.f, an0 = 0.f, an1 = 0.f;
            #pragma unroll
            for (int i = 0; i < 4; ++i) {
                uint4 hv4 = hp[i];
                uint wds[4] = {hv4.x, hv4.y, hv4.z, hv4.w};
                #pragma unroll
                for (int k2 = 0; k2 < 4; ++k2) {
                    union { uint u; f16x2 h; } cv; cv.u = wds[k2];
                    const int ii = i * 4 + k2;
                    if (ii & 1) {
                        ar1 = __builtin_amdgcn_fdot2(cv.h, wh[0][ii], ar1, false);
                        az1 = __builtin_amdgcn_fdot2(cv.h, wh[1][ii], az1, false);
                        an1 = __builtin_amdgcn_fdot2(cv.h, wh[2][ii], an1, false);
                    } else {
                        ar0 = __builtin_amdgcn_fdot2(cv.h, wh[0][ii], ar0, false);
                        az0 = __builtin_amdgcn_fdot2(cv.h, wh[1][ii], az0, false);
                        an0 = __builtin_amdgcn_fdot2(cv.h, wh[2][ii], an0, false);
                    }
                }
            }
            float sr = ar0 + ar1, sz = az0 + az1, sn = an0 + an1;
            sr = dpp_add_xor2(dpp_add_xor1(sr));
            sz = dpp_add_xor2(dpp_add_xor1(sz));
            sn = dpp_add_xor2(dpp_add_xor1(sn));

            // epilogue: all lanes, branch-free (full sums live in all 4 lanes)
            float r = sigf2(gr_c + bh0 + sr);
            float z = sigf2(gz_c + bh1 + sz);
            float n = tanh2(gn_c + r * (bh2 + sn));
            h = (1.f - z) * n + z * h_pre;
            if (q == 0)
                Hraw[(base + (long)tile * TB + ts) * P_ + j] = h;

            d_c = d_n; ht_c = ht_n; gr_c = gr_n; gz_c = gz_n; gn_c = gn_n;
            sb ^= 1;
        }

        // stage next tile (writes s_in[cur^1]; no conflict with this tile's
        // reads of s_in[cur]; precise vmcnt on p0..p2 happens here, once/tile)
        if (has_next) {
            uint4* d = (uint4*)s_in[cur ^ 1];
            d[tid] = p0; d[512 + tid] = p1; d[1024 + tid] = p2;
            bar_lds();
            cur ^= 1;
        }
    }
}

// ---------------------------------------------------------------------------
// Kernel 3: head. [unchanged]
// ---------------------------------------------------------------------------
__global__ __launch_bounds__(256) void k_head(
    const float* __restrict__ Hraw, const float* __restrict__ STD,
    const float* __restrict__ Z, const int* __restrict__ idx_map,
    const float* __restrict__ W1, const float* __restrict__ b1,
    const float* __restrict__ W2,
    float* __restrict__ eta, float* __restrict__ Hagg,
    float* __restrict__ mask_out)
{
    __shared__ float sW1[HH * FDIM];
    __shared__ float sb1[HH], sW2[HH];
    __shared__ float spart[TA][4];

    const int tid = threadIdx.x, b = blockIdx.x;
    for (int i = tid; i < HH * FDIM; i += 256) sW1[i] = W1[i];
    if (tid < HH) { sb1[tid] = b1[tid]; sW2[tid] = W2[tid]; }
    __syncthreads();

    const int s = tid >> 2, p = tid & 3;
    const int idx = idx_map[b * TA + s];
    const int valid = idx >= 0;
    const int tt = valid ? idx : 0;
    const float* hrow = Hraw + ((long)b * TR + tt) * H_;

    float acc[16];
    #pragma unroll
    for (int uu = 0; uu < 16; ++uu) acc[uu] = sb1[p * 16 + uu];

    for (int f = 0; f < FDIM; ++f) {
        float feat;
        if (f < H_)              feat = valid ? hrow[f] : 0.f;
        else if (f < H_ + PSTD)  feat = STD[((long)b * TA + s) * PSTD + (f - H_)];
        else                     feat = Z[b * PSTAT + (f - H_ - PSTD)];
        #pragma unroll
        for (int uu = 0; uu < 16; ++uu)
            acc[uu] += feat * sW1[(p * 16 + uu) * FDIM + f];
    }

    float pe = 0.f;
    #pragma unroll
    for (int uu = 0; uu < 16; ++uu) {
        float a = acc[uu];
        pe += (a > 0.f ? a : 0.f) * sW2[p * 16 + uu];
    }
    spart[s][p] = pe;

    for (int e = 0; e < 32; ++e) {
        int ee = p * 32 + e;
        Hagg[((long)b * TA + s) * H_ + ee] = valid ? hrow[ee] : 0.f;
    }
    if (p == 0) mask_out[b * TA + s] = valid ? 1.f : 0.f;

    __syncthreads();
    if (tid < TA)
        eta[b * TA + tid] = spart[tid][0] + spart[tid][1] + spart[tid][2] + spart[tid][3];
}

// ---------------------------------------------------------------------------
extern "C" void kernel_launch(void* const* d_in, const int* in_sizes, int n_in,
                              void* d_out, int out_size, void* d_ws, size_t ws_size,
                              hipStream_t stream)
{
    const float* X     = (const float*)d_in[0];
    const float* M     = (const float*)d_in[1];
    const float* DT    = (const float*)d_in[2];
    const float* STD   = (const float*)d_in[3];
    const float* Z     = (const float*)d_in[4];
    const int*   idxm  = (const int*)  d_in[5];
    const float* xmean = (const float*)d_in[6];
    const float* Wd    = (const float*)d_in[7];
    const float* bd    = (const float*)d_in[8];
    const float* Wih   = (const float*)d_in[9];
    const float* bih   = (const float*)d_in[10];
    const float* Whh   = (const float*)d_in[11];
    const float* bhh   = (const float*)d_in[12];
    const float* W1    = (const float*)d_in[13];
    const float* b1    = (const float*)d_in[14];
    const float* W2    = (const float*)d_in[15];

    const long RROWS = (long)B_ * TR;   // 131072
    char* ws = (char*)d_ws;
    size_t off = 0;
    ushort* gi_ws   = (ushort*)(ws + off); off += (size_t)RROWS * NG * 2;
    ushort* htil_ws = (ushort*)(ws + off); off += (size_t)RROWS * P_ * 2;
    float*  delta_ws= (float*) (ws + off); off += (size_t)RROWS * P_ * 4;
    ushort* wih_b   = (ushort*)(ws + off); off += (size_t)NG * KI * 2;
    ushort* wd_b    = (ushort*)(ws + off); off += (size_t)H_ * P_ * 2;

    float* out   = (float*)d_out;
    float* eta   = out;                                  // [256,64]
    float* Hraw  = out + 16384;                          // [256,512,128]
    float* Hagg  = out + 16384 + (long)B_ * TR * H_;     // [256,64,128]
    float* maskO = Hagg + (long)B_ * TA * H_;            // [256,64]

    hipLaunchKernelGGL(k_convert, dim3(384), dim3(256), 0, stream,
                       Wih, Wd, wih_b, wd_b);
    hipLaunchKernelGGL(k_gemm, dim3(2048), dim3(256), 0, stream,
                       X, M, DT, xmean, wih_b, wd_b, bih, bd,
                       gi_ws, htil_ws, delta_ws);
    hipLaunchKernelGGL(k_scan, dim3(256), dim3(512), 0, stream,
                       gi_ws, htil_ws, delta_ws, Whh, bhh, Hraw);
    hipLaunchKernelGGL(k_head, dim3(256), dim3(256), 0, stream,
                       Hraw, STD, Z, idxm, W1, b1, W2, eta, Hagg, maskO);
}

// Round 9
// 641.542 us; speedup vs baseline: 2.0610x; 1.0752x over previous
//
#include <hip/hip_runtime.h>
#include <hip/hip_bf16.h>
#include <hip/hip_fp16.h>

// Problem constants
#define B_    256
#define TR    512
#define P_    128
#define H_    128
#define NG    384      // 3*H
#define KI    256      // 2*P
#define TA    64
#define PSTD  32
#define PSTAT 16
#define HH    64       // HEAD_H
#define FDIM  176      // H + P_STD + P_STATIC

#define TB    16       // scan time-tile (LDS-resident steps)
#define NT    (TR/TB)  // 32 tiles
#define TILE_BYTES 24576   // gi(12288) + htil(4096) + delta(8192) per tile

typedef __attribute__((ext_vector_type(8))) short short8;
typedef __attribute__((ext_vector_type(4))) float f32x4;
typedef _Float16 f16;
typedef __attribute__((ext_vector_type(2))) _Float16 f16x2;

// ---- helpers ----
__device__ __forceinline__ float bf2f(ushort u) {
    union { uint i; float f; } v; v.i = ((uint)u) << 16; return v.f;
}
__device__ __forceinline__ ushort f2bf(float f) {
    union { float f; uint u; } v; v.f = f;
    uint u = v.u;
    uint r = (u + 0x7fffu + ((u >> 16) & 1u)) >> 16;  // RTNE
    return (ushort)r;
}
__device__ __forceinline__ float bflo(uint u) {   // low bf16 of a pair-word
    union { uint i; float f; } v; v.i = u << 16; return v.f;
}
__device__ __forceinline__ float bfhi(uint u) {   // high bf16 of a pair-word
    union { uint i; float f; } v; v.i = u & 0xffff0000u; return v.f;
}
__device__ __forceinline__ float tanhf_fast(float x) {
    float ax = fabsf(x);
    float e = __expf(-2.f * ax);
    float r = (1.f - e) / (1.f + e);
    return copysignf(r, x);
}
// branch-free scan transcendentals (validated r7/r8)
__device__ __forceinline__ float sigf2(float x) {
    return __builtin_amdgcn_rcpf(1.f + __expf(-x));
}
__device__ __forceinline__ float tanh2(float x) {
    return 1.f - 2.f * __builtin_amdgcn_rcpf(1.f + __expf(2.f * x));
}
// LDS-only barrier, no memory clobber (validated r8: no vmcnt drain)
__device__ __forceinline__ void bar_lds() {
    __builtin_amdgcn_sched_barrier(0);
    __asm__ volatile("s_waitcnt lgkmcnt(0)");
    __builtin_amdgcn_s_barrier();
    __builtin_amdgcn_sched_barrier(0);
}
// DPP pair add: lanes 2m <-> 2m+1 (quad_perm [1,0,3,2]); both lanes get sum
__device__ __forceinline__ float dpp_add_xor1(float x) {
    int r = __builtin_amdgcn_mov_dpp(__float_as_int(x), 0xB1, 0xF, 0xF, true);
    return x + __int_as_float(r);
}

// ---------------------------------------------------------------------------
// Kernel 0: convert Wih, Wd to bf16  [unchanged]
// ---------------------------------------------------------------------------
__global__ __launch_bounds__(256) void k_convert(
    const float* __restrict__ Wih, const float* __restrict__ Wd,
    ushort* __restrict__ wih_b, ushort* __restrict__ wd_b)
{
    int i = blockIdx.x * 256 + threadIdx.x;
    if (i < NG * KI) wih_b[i] = f2bf(Wih[i]);
    if (i < H_ * P_) wd_b[i]  = f2bf(Wd[i]);
}

// ---------------------------------------------------------------------------
// Kernel 1: fused elementwise + GEMM (MFMA bf16 16x16x32).
//   v11 change: gi/htil staged in TIME-PAIR interleaved layout so the scan
//   reads one b32 per gate per 2 steps:
//     gi_ws  : [pair][gate][j][2]  (ushort idx = (t>>1)*768 + g*256 + j*2 + (t&1))
//     htil_ws: [pair][j][2]        (ushort idx = (t>>1)*256 + j*2 + (t&1))
//   Only the sOut staging indices change; uint4 copy-out is layout-agnostic
//   and per-tile global byte ranges are unchanged (t0*384 == (t0/2)*768).
// ---------------------------------------------------------------------------
#define SA 392   // padded LDS row stride in bf16 elems (also >= 384 for staging)

__global__ __launch_bounds__(256, 2) void k_gemm(
    const float* __restrict__ X, const float* __restrict__ M,
    const float* __restrict__ DT, const float* __restrict__ xmean,
    const ushort* __restrict__ wih_b, const ushort* __restrict__ wd_b,
    const float* __restrict__ bih, const float* __restrict__ bd,
    ushort* __restrict__ gi_ws, ushort* __restrict__ htil_ws,
    float* __restrict__ delta_ws)
{
    __shared__ __align__(16) ushort sA[64 * SA];   // 50176 B; reused for staging
    const int tid = threadIdx.x;
    const long r0 = (long)blockIdx.x * 64;

    // ---- build A tile (64 rows x [x_dec|m|x_hat]) + delta (coalesced f32) ----
    #pragma unroll 4
    for (int i = 0; i < 32; ++i) {
        int idx = i * 256 + tid;
        int rl = idx >> 7, k = idx & 127;
        long g = (r0 + rl) * 128 + k;
        float x = X[g], m = M[g], dt = DT[g], xm = xmean[k];
        float delta = 1.f / (1.f + __expf(dt));   // sigmoid(-dt)
        float xh = m * x + (1.f - m) * xm;
        float xd = m * x + (1.f - m) * (delta * xh + (1.f - delta) * xm);
        sA[rl * SA + k]       = f2bf(xd);
        sA[rl * SA + 128 + k] = f2bf(m);
        sA[rl * SA + 256 + k] = f2bf(xh);
        delta_ws[g] = delta;
    }
    __syncthreads();

    const int wv   = tid >> 6;        // wave 0..3 -> gi col slice [96w,96w+96)
    const int lane = tid & 63;
    const int l16  = lane & 15;       // A row idx / B col idx / C col idx
    const int q    = lane >> 4;       // quad: A k-offset q*8 / C rows q*4+reg

    // ---- gi: acc[rt][nt], rt = row-tile (16 rows), nt = col-tile in slice ----
    f32x4 acc[4][6];
    #pragma unroll
    for (int rt = 0; rt < 4; ++rt)
        #pragma unroll
        for (int nt = 0; nt < 6; ++nt) acc[rt][nt] = (f32x4){0.f, 0.f, 0.f, 0.f};

    const int nb = 96 * wv;
    #pragma unroll
    for (int ks = 0; ks < 8; ++ks) {
        short8 a[4];
        #pragma unroll
        for (int rt = 0; rt < 4; ++rt)
            a[rt] = *(const short8*)&sA[(rt * 16 + l16) * SA + ks * 32 + q * 8];
        #pragma unroll
        for (int nt = 0; nt < 6; ++nt) {
            const short8 b = *(const short8*)&wih_b[(size_t)(nb + nt * 16 + l16) * KI + ks * 32 + q * 8];
            #pragma unroll
            for (int rt = 0; rt < 4; ++rt)
                acc[rt][nt] = __builtin_amdgcn_mfma_f32_16x16x32_bf16(a[rt], b, acc[rt][nt], 0, 0, 0);
        }
    }

    // ---- htil: acc2[rt][nt2], col slice [32w,32w+32), K=128 (A cols 256+) ----
    f32x4 acc2[4][2];
    #pragma unroll
    for (int rt = 0; rt < 4; ++rt)
        #pragma unroll
        for (int nt = 0; nt < 2; ++nt) acc2[rt][nt] = (f32x4){0.f, 0.f, 0.f, 0.f};

    const int nb2 = 32 * wv;
    #pragma unroll
    for (int ks = 0; ks < 4; ++ks) {
        short8 a[4];
        #pragma unroll
        for (int rt = 0; rt < 4; ++rt)
            a[rt] = *(const short8*)&sA[(rt * 16 + l16) * SA + 256 + ks * 32 + q * 8];
        #pragma unroll
        for (int nt = 0; nt < 2; ++nt) {
            const short8 b = *(const short8*)&wd_b[(size_t)(nb2 + nt * 16 + l16) * P_ + ks * 32 + q * 8];
            #pragma unroll
            for (int rt = 0; rt < 4; ++rt)
                acc2[rt][nt] = __builtin_amdgcn_mfma_f32_16x16x32_bf16(a[rt], b, acc2[rt][nt], 0, 0, 0);
        }
    }

    __syncthreads();   // all sA reads done; safe to overwrite with staging

    // ---- stage gi (bf16) PAIR-INTERLEAVED: idx=(row>>1)*768+g*256+j*2+(row&1)
    ushort* sOut = sA;
    #pragma unroll
    for (int nt = 0; nt < 6; ++nt) {
        const int n = nb + nt * 16 + l16;
        const float bi = bih[n];
        const int gpart = (n >> 7) * 256 + (n & 127) * 2;
        #pragma unroll
        for (int rt = 0; rt < 4; ++rt) {
            #pragma unroll
            for (int reg = 0; reg < 4; ++reg) {
                int row = rt * 16 + q * 4 + reg;
                sOut[(row >> 1) * 768 + gpart + (row & 1)] = f2bf(acc[rt][nt][reg] + bi);
            }
        }
    }
    __syncthreads();

    // ---- coalesced contiguous store: 64*384 bf16 = 3072 uint4 ----
    {
        uint4* dst = (uint4*)(gi_ws + (size_t)r0 * NG);
        const uint4* src = (const uint4*)sOut;
        #pragma unroll
        for (int i = 0; i < 12; ++i) dst[tid + 256 * i] = src[tid + 256 * i];
    }
    __syncthreads();   // uint4 LDS reads retired; safe to restage

    // ---- stage htil (bf16) PAIR-INTERLEAVED: idx=(row>>1)*256+j*2+(row&1) ----
    #pragma unroll
    for (int nt = 0; nt < 2; ++nt) {
        const int n = nb2 + nt * 16 + l16;
        const float bi = bd[n];
        #pragma unroll
        for (int rt = 0; rt < 4; ++rt) {
            #pragma unroll
            for (int reg = 0; reg < 4; ++reg) {
                int row = rt * 16 + q * 4 + reg;
                sOut[(row >> 1) * 256 + n * 2 + (row & 1)] = f2bf(tanhf_fast(acc2[rt][nt][reg] + bi));
            }
        }
    }
    __syncthreads();

    // ---- coalesced store: 64*128 bf16 = 1024 uint4 ----
    {
        uint4* dst = (uint4*)(htil_ws + (size_t)r0 * P_);
        const uint4* src = (const uint4*)sOut;
        #pragma unroll
        for (int i = 0; i < 4; ++i) dst[tid + 256 * i] = src[tid + 256 * i];
    }
}

// ---------------------------------------------------------------------------
// Kernel 2: recurrent scan v11 — 4 waves (256 thr), pair-interleaved gates.
//   LDS-pipe accounting of v10 (8 waves): 32 b128 (h, invariant) + 40 scalar
//   gate reads + writes ~ 650cy/step serialized on the one LDS unit per CU.
//   v11: j=tid>>1, q=tid&1 (64 k per lane: 8 b128, 96 fdot2, wh[3][32]);
//   gates read as bf16 PAIRS (one b32 per gate per 2 steps): scalar reads
//   5/step -> 3/step; 4-wave barrier; single dpp_xor1 reduce.
// ---------------------------------------------------------------------------
#define LOADP(SFX, TP) {                                                     \
    gr##SFX = *(const uint*)&sgi[(TP) * 768 + (j << 1)];                     \
    gz##SFX = *(const uint*)&sgi[(TP) * 768 + 256 + (j << 1)];               \
    gn##SFX = *(const uint*)&sgi[(TP) * 768 + 512 + (j << 1)];               \
    ht##SFX = *(const uint*)&sht[(TP) * 256 + (j << 1)];                     \
    dl##SFX##0 = sdl[(TP) * 256 + j];                                        \
    dl##SFX##1 = sdl[(TP) * 256 + 128 + j];                                  \
}

// One step. PH=0 uses lo bf16 / dl0, PH=1 uses hi / dl1, of pair SFX.
#define SCANSTEP(TS, SFX, PH) {                                              \
    float d_c  = PH ? dl##SFX##1 : dl##SFX##0;                               \
    float ht_c = PH ? bfhi(ht##SFX) : bflo(ht##SFX);                         \
    float h_pre = d_c * h + (1.f - d_c) * ht_c;                              \
    if (q == 0) ((f16*)s_hp16[sb])[j] = (f16)h_pre;                          \
    bar_lds();                                                               \
    const uint4* hp = (const uint4*)((const char*)s_hp16[sb] + q * 128);     \
    float ar0 = 0.f, ar1 = 0.f, az0 = 0.f, az1 = 0.f, an0 = 0.f, an1 = 0.f;  \
    _Pragma("unroll")                                                        \
    for (int r8 = 0; r8 < 8; ++r8) {                                         \
        uint4 hv4 = hp[r8];                                                  \
        uint wds[4] = {hv4.x, hv4.y, hv4.z, hv4.w};                          \
        _Pragma("unroll")                                                    \
        for (int c = 0; c < 4; ++c) {                                        \
            union { uint u; f16x2 h; } cv; cv.u = wds[c];                    \
            const int ii = r8 * 4 + c;                                       \
            if (ii & 1) {                                                    \
                ar1 = __builtin_amdgcn_fdot2(cv.h, wh[0][ii], ar1, false);   \
                az1 = __builtin_amdgcn_fdot2(cv.h, wh[1][ii], az1, false);   \
                an1 = __builtin_amdgcn_fdot2(cv.h, wh[2][ii], an1, false);   \
            } else {                                                         \
                ar0 = __builtin_amdgcn_fdot2(cv.h, wh[0][ii], ar0, false);   \
                az0 = __builtin_amdgcn_fdot2(cv.h, wh[1][ii], az0, false);   \
                an0 = __builtin_amdgcn_fdot2(cv.h, wh[2][ii], an0, false);   \
            }                                                                \
        }                                                                    \
    }                                                                        \
    float sr = dpp_add_xor1(ar0 + ar1);                                      \
    float sz = dpp_add_xor1(az0 + az1);                                      \
    float sn = dpp_add_xor1(an0 + an1);                                      \
    float gr_c = PH ? bfhi(gr##SFX) : bflo(gr##SFX);                         \
    float gz_c = PH ? bfhi(gz##SFX) : bflo(gz##SFX);                         \
    float gn_c = PH ? bfhi(gn##SFX) : bflo(gn##SFX);                         \
    float r = sigf2(gr_c + bh0 + sr);                                        \
    float z = sigf2(gz_c + bh1 + sz);                                        \
    float n = tanh2(gn_c + r * (bh2 + sn));                                  \
    h = (1.f - z) * n + z * h_pre;                                           \
    if (q == 0)                                                              \
        Hraw[(base + (long)tile * TB + (TS)) * P_ + j] = h;                  \
    sb ^= 1;                                                                 \
}

// pair iteration: steps 2tp, 2tp+1 with pair CURS; prefetch pair NXTS (tp+1)
#define PAIRSTEP(TP, CURS, NXTS) {                                           \
    SCANSTEP(2 * (TP), CURS, 0);                                             \
    if ((TP) < 7) LOADP(NXTS, (TP) + 1);                                     \
    SCANSTEP(2 * (TP) + 1, CURS, 1);                                         \
}

__global__ __launch_bounds__(256, 1) void k_scan(
    const ushort* __restrict__ gi_ws, const ushort* __restrict__ htil_ws,
    const float* __restrict__ delta_ws, const float* __restrict__ Whh,
    const float* __restrict__ bhh, float* __restrict__ Hraw)
{
    __shared__ __align__(16) char s_in[2][TILE_BYTES];  // 49152 B
    __shared__ __align__(16) uint s_hp16[2][68];        //   544 B packed f16

    const int tid = threadIdx.x;
    const int b   = blockIdx.x;
    const int j   = tid >> 1;          // 0..127
    const int q   = tid & 1;           // k-half: q*64 .. q*64+63
    const long base = (long)b * TR;

    // packed f16 weights for this lane's k-half: wh[g][i] = W[j][q*64+2i..+1]
    f16x2 wh[3][32];
    #pragma unroll
    for (int g = 0; g < 3; ++g) {
        const float* wp = Whh + ((g << 7) + j) * H_ + (q << 6);
        #pragma unroll
        for (int i = 0; i < 32; ++i) {
            f16x2 v;
            v[0] = (f16)wp[2 * i];
            v[1] = (f16)wp[2 * i + 1];
            wh[g][i] = v;
        }
    }
    const float bh0 = bhh[j], bh1 = bhh[128 + j], bh2 = bhh[256 + j];

    // ---- stage tile 0 (6 uint4 per thread, branch-free mapping) ----
    {
        const uint4* gi4 = (const uint4*)(gi_ws   + (size_t)base * NG);
        const uint4* ht4 = (const uint4*)(htil_ws + (size_t)base * P_);
        const uint4* dl4 = (const uint4*)(delta_ws + (size_t)base * P_);
        uint4 p0 = gi4[tid], p1 = gi4[256 + tid], p2 = gi4[512 + tid];
        uint4 p3 = ht4[tid], p4 = dl4[tid], p5 = dl4[256 + tid];
        uint4* d = (uint4*)s_in[0];
        d[tid] = p0; d[256 + tid] = p1; d[512 + tid] = p2;
        d[768 + tid] = p3; d[1024 + tid] = p4; d[1280 + tid] = p5;
    }
    bar_lds();

    int cur = 0, sb = 0;
    float h = 0.f;

    for (int tile = 0; tile < NT; ++tile) {
        uint4 p0, p1, p2, p3, p4, p5;
        const int has_next = (tile + 1 < NT);
        if (has_next) {
            const long tn = base + (long)(tile + 1) * TB;
            const uint4* gi4 = (const uint4*)(gi_ws   + (size_t)tn * NG);
            const uint4* ht4 = (const uint4*)(htil_ws + (size_t)tn * P_);
            const uint4* dl4 = (const uint4*)(delta_ws + (size_t)tn * P_);
            p0 = gi4[tid]; p1 = gi4[256 + tid]; p2 = gi4[512 + tid];
            p3 = ht4[tid]; p4 = dl4[tid]; p5 = dl4[256 + tid];
        }

        const ushort* sgi = (const ushort*)s_in[cur];           // 6144 ush
        const ushort* sht = (const ushort*)(s_in[cur] + 12288); // 2048 ush
        const float*  sdl = (const float*) (s_in[cur] + 16384); // 2048 f32

        uint grA, gzA, gnA, htA; float dlA0, dlA1;
        uint grB, gzB, gnB, htB; float dlB0, dlB1;
        LOADP(A, 0);

        PAIRSTEP(0, A, B);
        PAIRSTEP(1, B, A);
        PAIRSTEP(2, A, B);
        PAIRSTEP(3, B, A);
        PAIRSTEP(4, A, B);
        PAIRSTEP(5, B, A);
        PAIRSTEP(6, A, B);
        PAIRSTEP(7, B, A);

        if (has_next) {
            uint4* d = (uint4*)s_in[cur ^ 1];
            d[tid] = p0; d[256 + tid] = p1; d[512 + tid] = p2;
            d[768 + tid] = p3; d[1024 + tid] = p4; d[1280 + tid] = p5;
            bar_lds();
            cur ^= 1;
        }
    }
}

// ---------------------------------------------------------------------------
// Kernel 3: head. [unchanged]
// ---------------------------------------------------------------------------
__global__ __launch_bounds__(256) void k_head(
    const float* __restrict__ Hraw, const float* __restrict__ STD,
    const float* __restrict__ Z, const int* __restrict__ idx_map,
    const float* __restrict__ W1, const float* __restrict__ b1,
    const float* __restrict__ W2,
    float* __restrict__ eta, float* __restrict__ Hagg,
    float* __restrict__ mask_out)
{
    __shared__ float sW1[HH * FDIM];
    __shared__ float sb1[HH], sW2[HH];
    __shared__ float spart[TA][4];

    const int tid = threadIdx.x, b = blockIdx.x;
    for (int i = tid; i < HH * FDIM; i += 256) sW1[i] = W1[i];
    if (tid < HH) { sb1[tid] = b1[tid]; sW2[tid] = W2[tid]; }
    __syncthreads();

    const int s = tid >> 2, p = tid & 3;
    const int idx = idx_map[b * TA + s];
    const int valid = idx >= 0;
    const int tt = valid ? idx : 0;
    const float* hrow = Hraw + ((long)b * TR + tt) * H_;

    float acc[16];
    #pragma unroll
    for (int uu = 0; uu < 16; ++uu) acc[uu] = sb1[p * 16 + uu];

    for (int f = 0; f < FDIM; ++f) {
        float feat;
        if (f < H_)              feat = valid ? hrow[f] : 0.f;
        else if (f < H_ + PSTD)  feat = STD[((long)b * TA + s) * PSTD + (f - H_)];
        else                     feat = Z[b * PSTAT + (f - H_ - PSTD)];
        #pragma unroll
        for (int uu = 0; uu < 16; ++uu)
            acc[uu] += feat * sW1[(p * 16 + uu) * FDIM + f];
    }

    float pe = 0.f;
    #pragma unroll
    for (int uu = 0; uu < 16; ++uu) {
        float a = acc[uu];
        pe += (a > 0.f ? a : 0.f) * sW2[p * 16 + uu];
    }
    spart[s][p] = pe;

    for (int e = 0; e < 32; ++e) {
        int ee = p * 32 + e;
        Hagg[((long)b * TA + s) * H_ + ee] = valid ? hrow[ee] : 0.f;
    }
    if (p == 0) mask_out[b * TA + s] = valid ? 1.f : 0.f;

    __syncthreads();
    if (tid < TA)
        eta[b * TA + tid] = spart[tid][0] + spart[tid][1] + spart[tid][2] + spart[tid][3];
}

// ---------------------------------------------------------------------------
extern "C" void kernel_launch(void* const* d_in, const int* in_sizes, int n_in,
                              void* d_out, int out_size, void* d_ws, size_t ws_size,
                              hipStream_t stream)
{
    const float* X     = (const float*)d_in[0];
    const float* M     = (const float*)d_in[1];
    const float* DT    = (const float*)d_in[2];
    const float* STD   = (const float*)d_in[3];
    const float* Z     = (const float*)d_in[4];
    const int*   idxm  = (const int*)  d_in[5];
    const float* xmean = (const float*)d_in[6];
    const float* Wd    = (const float*)d_in[7];
    const float* bd    = (const float*)d_in[8];
    const float* Wih   = (const float*)d_in[9];
    const float* bih   = (const float*)d_in[10];
    const float* Whh   = (const float*)d_in[11];
    const float* bhh   = (const float*)d_in[12];
    const float* W1    = (const float*)d_in[13];
    const float* b1    = (const float*)d_in[14];
    const float* W2    = (const float*)d_in[15];

    const long RROWS = (long)B_ * TR;   // 131072
    char* ws = (char*)d_ws;
    size_t off = 0;
    ushort* gi_ws   = (ushort*)(ws + off); off += (size_t)RROWS * NG * 2;
    ushort* htil_ws = (ushort*)(ws + off); off += (size_t)RROWS * P_ * 2;
    float*  delta_ws= (float*) (ws + off); off += (size_t)RROWS * P_ * 4;
    ushort* wih_b   = (ushort*)(ws + off); off += (size_t)NG * KI * 2;
    ushort* wd_b    = (ushort*)(ws + off); off += (size_t)H_ * P_ * 2;

    float* out   = (float*)d_out;
    float* eta   = out;                                  // [256,64]
    float* Hraw  = out + 16384;                          // [256,512,128]
    float* Hagg  = out + 16384 + (long)B_ * TR * H_;     // [256,64,128]
    float* maskO = Hagg + (long)B_ * TA * H_;            // [256,64]

    hipLaunchKernelGGL(k_convert, dim3(384), dim3(256), 0, stream,
                       Wih, Wd, wih_b, wd_b);
    hipLaunchKernelGGL(k_gemm, dim3(2048), dim3(256), 0, stream,
                       X, M, DT, xmean, wih_b, wd_b, bih, bd,
                       gi_ws, htil_ws, delta_ws);
    hipLaunchKernelGGL(k_scan, dim3(256), dim3(256), 0, stream,
                       gi_ws, htil_ws, delta_ws, Whh, bhh, Hraw);
    hipLaunchKernelGGL(k_head, dim3(256), dim3(256), 0, stream,
                       Hraw, STD, Z, idxm, W1, b1, W2, eta, Hagg, maskO);
}